// Round 1
// baseline (2079.844 us; speedup 1.0000x reference)
//
#include <hip/hip_runtime.h>
#include <math.h>

#define NB 16
#define NS 4096
#define ND 1024
#define NM (NB * NS)

// workspace layout (float offsets)
#define WS_T       0                      // 16*1024
#define WS_SCORES  (16 * 1024)            // 16*4096
#define WS_WEIGHTS (WS_SCORES + NB * NS)  // 16*4096
#define WS_PART    (WS_WEIGHTS + NB * NS) // 16*16*1024

// ---------------- kernel 1: t[b][e] = b_in[e] + b_ctx[e] + context[b].W_ctx[e] ----------------
__global__ __launch_bounds__(256) void tvec_kernel(const float* __restrict__ context,
                                                   const float* __restrict__ W_ctx,
                                                   const float* __restrict__ b_in,
                                                   const float* __restrict__ b_ctx,
                                                   float* __restrict__ t) {
    __shared__ float ctx[ND];
    int b = blockIdx.y;
    int e = blockIdx.x * 256 + threadIdx.x;
    for (int i = threadIdx.x; i < ND; i += 256) ctx[i] = context[b * ND + i];
    __syncthreads();
    float acc = b_in[e] + b_ctx[e];
    const float4* wr = (const float4*)(W_ctx + (size_t)e * ND);
    const float4* cr = (const float4*)ctx;
    for (int k = 0; k < ND / 4; ++k) {
        float4 w = wr[k];
        float4 c = cr[k];
        acc += c.x * w.x + c.y * w.y + c.z * w.z + c.w * w.w;
    }
    t[b * ND + e] = acc;
}

// ---------------- kernel 2: scores[b,s] = sum_e tanh(x.W_in^T + t) * w_att[e] ----------------
// Tiled fp32 GEMM-reduce: 64 rows/block, N looped in 16 passes of 64, BK=16.
__global__ __launch_bounds__(256) void scores_kernel(const float* __restrict__ x,
                                                     const float* __restrict__ W_in,
                                                     const float* __restrict__ t,
                                                     const float* __restrict__ w_att,
                                                     float* __restrict__ scores) {
    __shared__ float xs[16][68];   // [k][row], padded: 68*4=272B row stride (16B aligned)
    __shared__ float wt[16][68];   // [k][e]
    __shared__ float tsh[ND];
    __shared__ float wash[ND];

    int tid = threadIdx.x;
    int row0 = blockIdx.x * 64;
    int b = row0 >> 12;  // 4096 rows per batch; 64 | 4096 so no block crosses b

    for (int i = tid; i < ND; i += 256) {
        tsh[i] = t[b * ND + i];
        wash[i] = w_att[i];
    }

    int lrow = tid >> 2, kq = tid & 3;   // loader: 64 rows x 4 float4s
    int tr = tid >> 4, tc = tid & 15;    // compute: 16x16 threads, 4x4 microtile

    float sp[4] = {0.f, 0.f, 0.f, 0.f};

    for (int ep = 0; ep < 16; ++ep) {
        int e0 = ep * 64;
        float acc[4][4] = {};
        for (int kt = 0; kt < 64; ++kt) {
            int k0 = kt * 16;
            __syncthreads();
            float4 xv = *(const float4*)&x[(size_t)(row0 + lrow) * ND + k0 + kq * 4];
            float4 wv = *(const float4*)&W_in[(size_t)(e0 + lrow) * ND + k0 + kq * 4];
            xs[kq * 4 + 0][lrow] = xv.x;
            xs[kq * 4 + 1][lrow] = xv.y;
            xs[kq * 4 + 2][lrow] = xv.z;
            xs[kq * 4 + 3][lrow] = xv.w;
            wt[kq * 4 + 0][lrow] = wv.x;
            wt[kq * 4 + 1][lrow] = wv.y;
            wt[kq * 4 + 2][lrow] = wv.z;
            wt[kq * 4 + 3][lrow] = wv.w;
            __syncthreads();
#pragma unroll
            for (int kk = 0; kk < 16; ++kk) {
                float4 av = *(const float4*)&xs[kk][tr * 4];
                float4 bv = *(const float4*)&wt[kk][tc * 4];
                float a[4] = {av.x, av.y, av.z, av.w};
                float bb[4] = {bv.x, bv.y, bv.z, bv.w};
#pragma unroll
                for (int i = 0; i < 4; ++i)
#pragma unroll
                    for (int j = 0; j < 4; ++j) acc[i][j] += a[i] * bb[j];
            }
        }
        // epilogue for this e-pass: tanh + dot with w_att
#pragma unroll
        for (int i = 0; i < 4; ++i) {
            float c = 0.f;
#pragma unroll
            for (int j = 0; j < 4; ++j) {
                int e = e0 + tc * 4 + j;
                c += tanhf(acc[i][j] + tsh[e]) * wash[e];
            }
            sp[i] += c;
        }
    }
    // reduce across the 16 tc lanes (contiguous within wave)
#pragma unroll
    for (int i = 0; i < 4; ++i) {
        float v = sp[i];
        v += __shfl_xor(v, 1);
        v += __shfl_xor(v, 2);
        v += __shfl_xor(v, 4);
        v += __shfl_xor(v, 8);
        if (tc == 0) {
            int row = row0 + tr * 4 + i;
            scores[(size_t)b * NS + (row & (NS - 1))] = v;
        }
    }
}

// ---------------- kernel 3: softmax over S per batch ----------------
__global__ __launch_bounds__(256) void softmax_kernel(const float* __restrict__ scores,
                                                      float* __restrict__ weights) {
    int b = blockIdx.x;
    int tid = threadIdx.x;
    float v[16];
    float lmax = -1e30f;
#pragma unroll
    for (int i = 0; i < 16; ++i) {
        v[i] = scores[b * NS + tid + i * 256];
        lmax = fmaxf(lmax, v[i]);
    }
#pragma unroll
    for (int off = 32; off >= 1; off >>= 1) lmax = fmaxf(lmax, __shfl_xor(lmax, off));
    __shared__ float redm[4];
    int wave = tid >> 6;
    if ((tid & 63) == 0) redm[wave] = lmax;
    __syncthreads();
    float bmax = fmaxf(fmaxf(redm[0], redm[1]), fmaxf(redm[2], redm[3]));

    float lsum = 0.f;
#pragma unroll
    for (int i = 0; i < 16; ++i) {
        v[i] = expf(v[i] - bmax);
        lsum += v[i];
    }
#pragma unroll
    for (int off = 32; off >= 1; off >>= 1) lsum += __shfl_xor(lsum, off);
    __shared__ float reds[4];
    if ((tid & 63) == 0) reds[wave] = lsum;
    __syncthreads();
    float inv = 1.0f / (reds[0] + reds[1] + reds[2] + reds[3]);
#pragma unroll
    for (int i = 0; i < 16; ++i) weights[b * NS + tid + i * 256] = v[i] * inv;
}

// ---------------- kernel 4: partial weighted sums over s-chunks ----------------
__global__ __launch_bounds__(256) void wsum_kernel(const float* __restrict__ x,
                                                   const float* __restrict__ w,
                                                   float* __restrict__ part) {
    int sc = blockIdx.x, b = blockIdx.y;
    int d0 = threadIdx.x * 4;
    const float* xb = x + ((size_t)b * NS + sc * 256) * ND;
    const float* wb = w + b * NS + sc * 256;
    float4 acc = {0.f, 0.f, 0.f, 0.f};
    for (int ss = 0; ss < 256; ++ss) {
        float wv = wb[ss];
        float4 xv = *(const float4*)&xb[(size_t)ss * ND + d0];
        acc.x += wv * xv.x;
        acc.y += wv * xv.y;
        acc.z += wv * xv.z;
        acc.w += wv * xv.w;
    }
    *(float4*)&part[(size_t)(b * 16 + sc) * ND + d0] = acc;
}

// ---------------- kernel 5: reduce partials -> out ----------------
__global__ __launch_bounds__(256) void reduce_kernel(const float* __restrict__ part,
                                                     float* __restrict__ out) {
    int b = blockIdx.x;
    int d0 = threadIdx.x * 4;
    float4 acc = {0.f, 0.f, 0.f, 0.f};
#pragma unroll
    for (int sc = 0; sc < 16; ++sc) {
        float4 v = *(const float4*)&part[(size_t)(b * 16 + sc) * ND + d0];
        acc.x += v.x;
        acc.y += v.y;
        acc.z += v.z;
        acc.w += v.w;
    }
    *(float4*)&out[b * ND + d0] = acc;
}

extern "C" void kernel_launch(void* const* d_in, const int* in_sizes, int n_in,
                              void* d_out, int out_size, void* d_ws, size_t ws_size,
                              hipStream_t stream) {
    const float* x       = (const float*)d_in[0];
    const float* context = (const float*)d_in[1];
    const float* W_in    = (const float*)d_in[2];
    // b_in = d_in[3]
    const float* W_ctx   = (const float*)d_in[4];
    // b_ctx = d_in[5]
    const float* w_att   = (const float*)d_in[6];
    // b_att = d_in[7] — softmax is shift-invariant; b_att cancels.
    const float* b_in    = (const float*)d_in[3];
    const float* b_ctx   = (const float*)d_in[5];

    float* ws      = (float*)d_ws;
    float* t       = ws + WS_T;
    float* scores  = ws + WS_SCORES;
    float* weights = ws + WS_WEIGHTS;
    float* part    = ws + WS_PART;
    float* out     = (float*)d_out;

    tvec_kernel<<<dim3(ND / 256, NB), 256, 0, stream>>>(context, W_ctx, b_in, b_ctx, t);
    scores_kernel<<<dim3(NM / 64), 256, 0, stream>>>(x, W_in, t, w_att, scores);
    softmax_kernel<<<dim3(NB), 256, 0, stream>>>(scores, weights);
    wsum_kernel<<<dim3(16, NB), 256, 0, stream>>>(x, weights, part);
    reduce_kernel<<<dim3(NB), 256, 0, stream>>>(part, out);
}

// Round 2
// 369.305 us; speedup vs baseline: 5.6318x; 5.6318x over previous
//
#include <hip/hip_runtime.h>
#include <hip/hip_bf16.h>
#include <math.h>

#define NB 16
#define NS 4096
#define ND 1024
#define NM (NB * NS)

// workspace layout (float offsets)
#define WS_T       0                            // 16*1024 floats
#define WS_SCORES  (16 * 1024)                  // 16*4096
#define WS_WEIGHTS (WS_SCORES + NB * NS)        // 16*4096
#define WS_PART    (WS_WEIGHTS + NB * NS)       // 16*16*1024
#define WS_WBF16   (WS_PART + 16 * 16 * 1024)   // 1024*1024 ushorts (2MB)

typedef short v8s __attribute__((ext_vector_type(8)));
typedef float v4f __attribute__((ext_vector_type(4)));
typedef unsigned short ushort;

__device__ __forceinline__ ushort f2bf(float f) {
    __hip_bfloat16 h = __float2bfloat16(f);
    return *reinterpret_cast<ushort*>(&h);
}

__device__ __forceinline__ float fast_tanh(float x) {
    // tanh(x) = 1 - 2/(e^{2x}+1); saturates correctly at +-inf
    float e = __expf(2.0f * x);
    return 1.0f - 2.0f / (e + 1.0f);
}

// ---------------- kernel 0: W_in fp32 -> bf16 ----------------
__global__ __launch_bounds__(256) void convw_kernel(const float* __restrict__ W,
                                                    ushort* __restrict__ Wb) {
    int flat = blockIdx.x * 256 + threadIdx.x;   // grid 512 -> 131072 threads
#pragma unroll
    for (int j = 0; j < 2; ++j) {
        int idx = flat + j * 131072;             // float4 index, 262144 total
        float4 v = ((const float4*)W)[idx];
        ushort4 o;
        o.x = f2bf(v.x); o.y = f2bf(v.y); o.z = f2bf(v.z); o.w = f2bf(v.w);
        ((ushort4*)Wb)[idx] = o;
    }
}

// ---------------- kernel 1: t[b][e] = b_in[e] + b_ctx[e] + context[b].W_ctx[e] ----------------
__global__ __launch_bounds__(256) void tvec_kernel(const float* __restrict__ context,
                                                   const float* __restrict__ W_ctx,
                                                   const float* __restrict__ b_in,
                                                   const float* __restrict__ b_ctx,
                                                   float* __restrict__ t) {
    __shared__ float ctx[ND];
    int b = blockIdx.y;
    int e = blockIdx.x * 256 + threadIdx.x;
    for (int i = threadIdx.x; i < ND; i += 256) ctx[i] = context[b * ND + i];
    __syncthreads();
    float acc = b_in[e] + b_ctx[e];
    const float4* wr = (const float4*)(W_ctx + (size_t)e * ND);
    const float4* cr = (const float4*)ctx;
    for (int k = 0; k < ND / 4; ++k) {
        float4 w = wr[k];
        float4 c = cr[k];
        acc += c.x * w.x + c.y * w.y + c.z * w.z + c.w * w.w;
    }
    t[b * ND + e] = acc;
}

// ---------------- kernel 2: scores via bf16 MFMA ----------------
// Block: 64 rows, 512 threads (8 waves). A (x rows, bf16, swizzled) resident in
// LDS for all K=1024. Each wave owns a 128-wide e-slice, 2 passes of 64 cols.
// B fragments read directly from global W_bf16 (L2-resident). No barriers in
// the K loop.
__global__ __launch_bounds__(512) void scores_mfma_kernel(const float* __restrict__ x,
                                                          const ushort* __restrict__ Wb,
                                                          const float* __restrict__ t,
                                                          const float* __restrict__ w_att,
                                                          float* __restrict__ scores) {
    __shared__ ushort As[64 * 1024];   // 128 KB, elem idx ^= (row&7)<<3 (16B swizzle)
    __shared__ float red[8][64];       // cross-wave score partials

    int tid = threadIdx.x;
    int row0 = blockIdx.x * 64;
    int b = row0 >> 12;                // 64 | 4096, no block crosses a batch

    // ---- stage A: 64 rows x 1024 cols fp32 -> bf16 LDS (read x exactly once) ----
    {
        int c4 = tid & 255;            // float4 column
        int rbase = tid >> 8;          // 0..1
        const float4* xf4 = (const float4*)x;
#pragma unroll 4
        for (int i = 0; i < 32; ++i) {
            int r = i * 2 + rbase;
            float4 v = xf4[(size_t)(row0 + r) * 256 + c4];
            ushort4 o;
            o.x = f2bf(v.x); o.y = f2bf(v.y); o.z = f2bf(v.z); o.w = f2bf(v.w);
            int k = c4 * 4;
            int swz = k ^ ((r & 7) << 3);
            *(ushort4*)&As[r * 1024 + swz] = o;
        }
    }
    __syncthreads();

    int w = tid >> 6;                  // wave 0..7
    int l = tid & 63;
    int l15 = l & 15;
    int kofs = (l >> 4) * 8;           // k sub-offset within fragment
    int xorv = (l & 7) << 3;           // A swizzle per lane

    float s[4][4];                     // per-lane score partials [m-frag][reg]
#pragma unroll
    for (int i = 0; i < 4; ++i)
#pragma unroll
        for (int j = 0; j < 4; ++j) s[i][j] = 0.f;

#pragma unroll
    for (int pass = 0; pass < 2; ++pass) {
        int n0 = w * 128 + pass * 64;

        // hoist t, w_att for this pass's 4 n-frags (per-lane col e)
        float t_r[4], w_r[4];
        const ushort* bp[4];
#pragma unroll
        for (int nf = 0; nf < 4; ++nf) {
            int e = n0 + nf * 16 + l15;
            t_r[nf] = t[b * ND + e];
            w_r[nf] = w_att[e];
            bp[nf] = Wb + (size_t)e * ND + kofs;
        }

        v4f acc[4][4];
#pragma unroll
        for (int i = 0; i < 4; ++i)
#pragma unroll
            for (int j = 0; j < 4; ++j) acc[i][j] = (v4f)(0.f);

#pragma unroll 2
        for (int ks = 0; ks < 32; ++ks) {
            int k0 = ks * 32;
            v8s af[4];
#pragma unroll
            for (int mf = 0; mf < 4; ++mf) {
                int elem = ((k0 + kofs) ^ xorv);
                af[mf] = *(const v8s*)&As[(mf * 16 + l15) * 1024 + elem];
            }
            v8s bf[4];
#pragma unroll
            for (int nf = 0; nf < 4; ++nf) bf[nf] = *(const v8s*)(bp[nf] + k0);
#pragma unroll
            for (int mf = 0; mf < 4; ++mf)
#pragma unroll
                for (int nf = 0; nf < 4; ++nf)
                    acc[mf][nf] = __builtin_amdgcn_mfma_f32_16x16x32_bf16(af[mf], bf[nf], acc[mf][nf], 0, 0, 0);
        }

        // epilogue: tanh + dot with w_att, accumulate per-row partials
#pragma unroll
        for (int mf = 0; mf < 4; ++mf)
#pragma unroll
            for (int nf = 0; nf < 4; ++nf)
#pragma unroll
                for (int r = 0; r < 4; ++r)
                    s[mf][r] += fast_tanh(acc[mf][nf][r] + t_r[nf]) * w_r[nf];
    }

    // reduce across the 16 cols held by lanes sharing l>>4
#pragma unroll
    for (int mf = 0; mf < 4; ++mf)
#pragma unroll
        for (int r = 0; r < 4; ++r) {
            float v = s[mf][r];
            v += __shfl_xor(v, 1);
            v += __shfl_xor(v, 2);
            v += __shfl_xor(v, 4);
            v += __shfl_xor(v, 8);
            s[mf][r] = v;
        }
    if (l15 == 0) {
#pragma unroll
        for (int mf = 0; mf < 4; ++mf)
#pragma unroll
            for (int r = 0; r < 4; ++r)
                red[w][mf * 16 + (l >> 4) * 4 + r] = s[mf][r];
    }
    __syncthreads();
    if (tid < 64) {
        float v = 0.f;
#pragma unroll
        for (int ww = 0; ww < 8; ++ww) v += red[ww][tid];
        scores[(size_t)b * NS + (row0 & (NS - 1)) + tid] = v;
    }
}

// ---------------- kernel 3: softmax over S per batch ----------------
__global__ __launch_bounds__(256) void softmax_kernel(const float* __restrict__ scores,
                                                      float* __restrict__ weights) {
    int b = blockIdx.x;
    int tid = threadIdx.x;
    float v[16];
    float lmax = -1e30f;
#pragma unroll
    for (int i = 0; i < 16; ++i) {
        v[i] = scores[b * NS + tid + i * 256];
        lmax = fmaxf(lmax, v[i]);
    }
#pragma unroll
    for (int off = 32; off >= 1; off >>= 1) lmax = fmaxf(lmax, __shfl_xor(lmax, off));
    __shared__ float redm[4];
    int wave = tid >> 6;
    if ((tid & 63) == 0) redm[wave] = lmax;
    __syncthreads();
    float bmax = fmaxf(fmaxf(redm[0], redm[1]), fmaxf(redm[2], redm[3]));

    float lsum = 0.f;
#pragma unroll
    for (int i = 0; i < 16; ++i) {
        v[i] = expf(v[i] - bmax);
        lsum += v[i];
    }
#pragma unroll
    for (int off = 32; off >= 1; off >>= 1) lsum += __shfl_xor(lsum, off);
    __shared__ float reds[4];
    if ((tid & 63) == 0) reds[wave] = lsum;
    __syncthreads();
    float inv = 1.0f / (reds[0] + reds[1] + reds[2] + reds[3]);
#pragma unroll
    for (int i = 0; i < 16; ++i) weights[b * NS + tid + i * 256] = v[i] * inv;
}

// ---------------- kernel 4: partial weighted sums over s-chunks ----------------
__global__ __launch_bounds__(256) void wsum_kernel(const float* __restrict__ x,
                                                   const float* __restrict__ w,
                                                   float* __restrict__ part) {
    int sc = blockIdx.x, b = blockIdx.y;
    int d0 = threadIdx.x * 4;
    const float* xb = x + ((size_t)b * NS + sc * 256) * ND;
    const float* wb = w + b * NS + sc * 256;
    float4 acc = {0.f, 0.f, 0.f, 0.f};
    for (int ss = 0; ss < 256; ++ss) {
        float wv = wb[ss];
        float4 xv = *(const float4*)&xb[(size_t)ss * ND + d0];
        acc.x += wv * xv.x;
        acc.y += wv * xv.y;
        acc.z += wv * xv.z;
        acc.w += wv * xv.w;
    }
    *(float4*)&part[(size_t)(b * 16 + sc) * ND + d0] = acc;
}

// ---------------- kernel 5: reduce partials -> out ----------------
__global__ __launch_bounds__(256) void reduce_kernel(const float* __restrict__ part,
                                                     float* __restrict__ out) {
    int b = blockIdx.x;
    int d0 = threadIdx.x * 4;
    float4 acc = {0.f, 0.f, 0.f, 0.f};
#pragma unroll
    for (int sc = 0; sc < 16; ++sc) {
        float4 v = *(const float4*)&part[(size_t)(b * 16 + sc) * ND + d0];
        acc.x += v.x;
        acc.y += v.y;
        acc.z += v.z;
        acc.w += v.w;
    }
    *(float4*)&out[b * ND + d0] = acc;
}

extern "C" void kernel_launch(void* const* d_in, const int* in_sizes, int n_in,
                              void* d_out, int out_size, void* d_ws, size_t ws_size,
                              hipStream_t stream) {
    const float* x       = (const float*)d_in[0];
    const float* context = (const float*)d_in[1];
    const float* W_in    = (const float*)d_in[2];
    const float* b_in    = (const float*)d_in[3];
    const float* W_ctx   = (const float*)d_in[4];
    const float* b_ctx   = (const float*)d_in[5];
    const float* w_att   = (const float*)d_in[6];
    // b_att (d_in[7]): softmax is shift-invariant; it cancels.

    float* ws      = (float*)d_ws;
    float* t       = ws + WS_T;
    float* scores  = ws + WS_SCORES;
    float* weights = ws + WS_WEIGHTS;
    float* part    = ws + WS_PART;
    ushort* wbf16  = (ushort*)(ws + WS_WBF16);
    float* out     = (float*)d_out;

    convw_kernel<<<dim3(512), 256, 0, stream>>>(W_in, wbf16);
    tvec_kernel<<<dim3(ND / 256, NB), 256, 0, stream>>>(context, W_ctx, b_in, b_ctx, t);
    scores_mfma_kernel<<<dim3(NM / 64), 512, 0, stream>>>(x, wbf16, t, w_att, scores);
    softmax_kernel<<<dim3(NB), 256, 0, stream>>>(scores, weights);
    wsum_kernel<<<dim3(16, NB), 256, 0, stream>>>(x, weights, part);
    reduce_kernel<<<dim3(NB), 256, 0, stream>>>(part, out);
}